// Round 4
// baseline (194.605 us; speedup 1.0000x reference)
//
#include <hip/hip_runtime.h>
#include <hip/hip_bf16.h>
#include <math.h>

#define BS   128
#define NT   25
#define CREC 107
#define CLOC 25
#define QN   1024      // H*W = 32*32 queries = columns of the transposed cost
#define INFD 1e18
#define KPL  16        // columns per lane (QN / 64)

// focal-loss matcher cost. Fast transcendentals: the matcher only needs the
// argmin/optimum, which is robust to ~1e-7 relative perturbation (optimum of
// a random continuous LP is unique with margin >> 1e-7).
__device__ __forceinline__ float focal_cost_f(float x) {
    float p   = 1.0f / (1.0f + __expf(-x));
    float neg = 0.75f * p * p * (-__logf(1.0f - p + 1e-8f));
    float pos = 0.25f * (1.0f - p) * (1.0f - p) * (-__logf(p + 1e-8f));
    return pos - neg;
}

// One block (256 thr = 4 waves) per batch.
// Phase B: row-reduction init  u[r] = min_j c[r][j], greedy-assign argmin cols
//          (rows parallel over waves, cost computed on the fly, no cost matrix).
// Phase C: JV shortest-augmenting-path ONLY for rows whose argmin collided
//          (~2-4/batch, ~1-3 iters each). All 4 waves execute the search
//          redundantly (identical register state, uniform control flow); LDS
//          mutations gated to wave 0 so barriers stay block-valid.
// Result = the unique optimal assignment = scipy's answer.
__global__ __launch_bounds__(256)
void hungarian_kernel(const float* __restrict__ rec, const float* __restrict__ loc,
                      const int* __restrict__ targets, int* __restrict__ pairq_g) {
    const int b    = blockIdx.x;
    const int tid  = threadIdx.x;
    const int wave = tid >> 6;
    const int lane = tid & 63;

    __shared__ int    way_s[QN + 1];
    __shared__ int    p_s[QN + 1];
    __shared__ double u_s[NT + 2];
    __shared__ float  rowmin_s[NT];
    __shared__ int    rowarg_s[NT];
    __shared__ int    unassigned_s[NT];
    __shared__ int    nun_s;

    for (int j = tid; j <= QN; j += 256) { p_s[j] = 0; way_s[j] = 0; }
    __syncthreads();

    // per-wave copy of this batch's targets (lane r holds targets[b,r])
    const int ts = (lane < NT) ? targets[b * NT + lane] : 0;

    // ---- Phase B: row minima (rows strided over waves, 2-deep prefetch) ----
    {
        float4 ra[4], la[4], rb[4], lb[4];
        int r = wave;
        if (r < NT) {
            int tc = __shfl(ts, r);
            const float4* rr = (const float4*)(rec + ((size_t)b * CREC + tc) * QN);
            const float4* lr = (const float4*)(loc + ((size_t)b * CLOC + r) * QN);
            #pragma unroll
            for (int g = 0; g < 4; ++g) { ra[g] = rr[lane + 64 * g]; la[g] = lr[lane + 64 * g]; }
        }
        while (r < NT) {
            int rn = r + 4;
            if (rn < NT) {
                int tc = __shfl(ts, rn);
                const float4* rr = (const float4*)(rec + ((size_t)b * CREC + tc) * QN);
                const float4* lr = (const float4*)(loc + ((size_t)b * CLOC + rn) * QN);
                #pragma unroll
                for (int g = 0; g < 4; ++g) { rb[g] = rr[lane + 64 * g]; lb[g] = lr[lane + 64 * g]; }
            }
            float bestv = 1e30f; int bestq = QN + 2;
            #pragma unroll
            for (int g = 0; g < 4; ++g) {
                float cr[4] = { ra[g].x, ra[g].y, ra[g].z, ra[g].w };
                float cl[4] = { la[g].x, la[g].y, la[g].z, la[g].w };
                #pragma unroll
                for (int m = 0; m < 4; ++m) {
                    float c = 2.0f * focal_cost_f(cr[m]) + focal_cost_f(cl[m]);
                    int q = 4 * lane + m + 256 * g;
                    if (c < bestv || (c == bestv && q < bestq)) { bestv = c; bestq = q; }
                }
            }
            #pragma unroll
            for (int off = 32; off; off >>= 1) {
                float ov = __shfl_xor(bestv, off);
                int   oq = __shfl_xor(bestq, off);
                if (ov < bestv || (ov == bestv && oq < bestq)) { bestv = ov; bestq = oq; }
            }
            if (lane == 0) { rowmin_s[r] = bestv; rowarg_s[r] = bestq; }
            if (rn < NT) {
                #pragma unroll
                for (int g = 0; g < 4; ++g) { ra[g] = rb[g]; la[g] = lb[g]; }
            }
            r = rn;
        }
    }
    __syncthreads();

    // ---- greedy tight assignment (serial, trivial) ----
    if (tid == 0) {
        nun_s = 0;
        for (int r = 0; r < NT; ++r) {
            u_s[r + 1] = (double)rowmin_s[r];
            int j = rowarg_s[r] + 1;
            if (p_s[j] == 0) p_s[j] = r + 1;
            else             unassigned_s[nun_s++] = r + 1;
        }
    }
    __syncthreads();
    const int nun = nun_s;

    // ---- Phase C: JV search for each unassigned row ----
    // lane owns columns q = 4*lane + m + 256*g (k = g*4+m), j = q+1
    double v[KPL];
    #pragma unroll
    for (int k = 0; k < KPL; ++k) v[k] = 0.0;

    for (int s = 0; s < nun; ++s) {
        const int i = unassigned_s[s];
        double minv[KPL];
        unsigned usedmask = 0;
        #pragma unroll
        for (int k = 0; k < KPL; ++k) minv[k] = INFD;

        int j0 = 0;
        for (int iter = 0; iter < QN + 2; ++iter) {
            int i0;
            if (j0 == 0) {
                i0 = i;
            } else {
                int q0 = j0 - 1;
                if (((q0 >> 2) & 63) == lane) {
                    int kk = ((q0 >> 8) << 2) | (q0 & 3);
                    usedmask |= 1u << kk;
                    minv[kk] = INFD;
                }
                i0 = p_s[j0];
            }
            const double ui0 = u_s[i0];
            const int    tr  = i0 - 1;
            const int    tc  = __shfl(ts, tr);
            const float4* rr = (const float4*)(rec + ((size_t)b * CREC + tc) * QN);
            const float4* lr = (const float4*)(loc + ((size_t)b * CLOC + tr) * QN);
            float cf[KPL];
            #pragma unroll
            for (int g = 0; g < 4; ++g) {
                float4 r4 = rr[lane + 64 * g];
                float4 l4 = lr[lane + 64 * g];
                cf[4 * g + 0] = 2.0f * focal_cost_f(r4.x) + focal_cost_f(l4.x);
                cf[4 * g + 1] = 2.0f * focal_cost_f(r4.y) + focal_cost_f(l4.y);
                cf[4 * g + 2] = 2.0f * focal_cost_f(r4.z) + focal_cost_f(l4.z);
                cf[4 * g + 3] = 2.0f * focal_cost_f(r4.w) + focal_cost_f(l4.w);
            }

            double bestv = INFD; int bestj = QN + 2;
            #pragma unroll
            for (int k = 0; k < KPL; ++k) {
                if (!(usedmask & (1u << k))) {
                    const int j = 1 + 4 * lane + (k & 3) + 256 * (k >> 2);
                    double cur = (double)cf[k] - ui0 - v[k];
                    if (cur < minv[k]) {
                        minv[k] = cur;
                        if (wave == 0) way_s[j] = j0;
                    }
                    double mv = minv[k];
                    if (mv < bestv || (mv == bestv && j < bestj)) { bestv = mv; bestj = j; }
                }
            }
            #pragma unroll
            for (int off = 32; off; off >>= 1) {
                double ov = __shfl_xor(bestv, off);
                int    oj = __shfl_xor(bestj, off);
                if (ov < bestv || (ov == bestv && oj < bestj)) { bestv = ov; bestj = oj; }
            }
            const double delta = bestv;
            const int j1 = bestj;

            #pragma unroll
            for (int k = 0; k < KPL; ++k) {
                if (usedmask & (1u << k)) v[k]    -= delta;
                else                      minv[k] -= delta;
            }
            if (wave == 0) {
                if (lane == 0) u_s[i] += delta;
                unsigned m = usedmask;
                while (m) {
                    int k = __ffs(m) - 1; m &= m - 1;
                    int j = 1 + 4 * lane + (k & 3) + 256 * (k >> 2);
                    u_s[p_s[j]] += delta;
                }
            }
            __syncthreads();

            j0 = j1;
            if (p_s[j0] == 0) break;
        }
        if (tid == 0) {
            int jj = j0;
            while (jj != 0) {
                int jn = way_s[jj];
                p_s[jj] = (jn == 0) ? i : p_s[jn];
                jj = jn;
            }
        }
        __syncthreads();
    }

    // emit matched pairs: column j assigned to target row p_s[j]-1
    for (int j = tid + 1; j <= QN; j += 256)
        if (p_s[j] > 0) pairq_g[b * NT + (p_s[j] - 1)] = j - 1;
}

// One wave per matched pair: CE over 107 (rec) and 25 (loc) classes at the
// matched query column. 3200 blocks => full latency hiding for the gathers.
__global__ __launch_bounds__(64)
void loss_kernel(const float* __restrict__ rec, const float* __restrict__ loc,
                 const int* __restrict__ targets, const int* __restrict__ pairq_g,
                 float* __restrict__ partial) {
    const int pid  = blockIdx.x;          // b*NT + t
    const int b    = pid / NT, t = pid % NT;
    const int lane = threadIdx.x;
    const int q    = pairq_g[pid];

    // rec CE over 107 classes at query q
    const float* rb = rec + (size_t)b * CREC * QN + q;
    float x0 = (lane < CREC)      ? rb[(size_t)lane * QN]        : -1e30f;
    float x1 = (lane + 64 < CREC) ? rb[(size_t)(lane + 64) * QN] : -1e30f;
    float mx = fmaxf(x0, x1);
    #pragma unroll
    for (int off = 32; off; off >>= 1) mx = fmaxf(mx, __shfl_xor(mx, off));
    float e = 0.0f;
    if (lane < CREC)      e += expf(x0 - mx);
    if (lane + 64 < CREC) e += expf(x1 - mx);
    #pragma unroll
    for (int off = 32; off; off >>= 1) e += __shfl_xor(e, off);
    float lse = mx + logf(e);

    // loc CE over 25 classes at query q, label = t
    const float* lb = loc + (size_t)b * CLOC * QN + q;
    float y = (lane < CLOC) ? lb[(size_t)lane * QN] : -1e30f;
    float my = y;
    #pragma unroll
    for (int off = 32; off; off >>= 1) my = fmaxf(my, __shfl_xor(my, off));
    float ey = (lane < CLOC) ? expf(y - my) : 0.0f;
    #pragma unroll
    for (int off = 32; off; off >>= 1) ey += __shfl_xor(ey, off);
    float lsey = my + logf(ey);

    if (lane == 0) {
        int lab = targets[pid];
        partial[pid]           = lse  - rb[(size_t)lab * QN];
        partial[BS * NT + pid] = lsey - lb[(size_t)t * QN];
    }
}

__global__ __launch_bounds__(256)
void finalize_kernel(const float* __restrict__ partial, float* __restrict__ out) {
    const int tid = threadIdx.x;
    float s0 = 0.0f, s1 = 0.0f;
    for (int i = tid; i < BS * NT; i += 256) {
        s0 += partial[i];
        s1 += partial[BS * NT + i];
    }
    __shared__ float a0[4], a1[4];
    #pragma unroll
    for (int off = 32; off; off >>= 1) { s0 += __shfl_xor(s0, off); s1 += __shfl_xor(s1, off); }
    if ((tid & 63) == 0) { a0[tid >> 6] = s0; a1[tid >> 6] = s1; }
    __syncthreads();
    if (tid == 0) {
        out[0] = (a0[0] + a0[1] + a0[2] + a0[3]) * (1.0f / (BS * NT));
        out[1] = (a1[0] + a1[1] + a1[2] + a1[3]) * (1.0f / (BS * NT));
    }
}

extern "C" void kernel_launch(void* const* d_in, const int* in_sizes, int n_in,
                              void* d_out, int out_size, void* d_ws, size_t ws_size,
                              hipStream_t stream) {
    (void)in_sizes; (void)n_in; (void)out_size; (void)ws_size;
    const float* rec     = (const float*)d_in[0];
    const float* loc     = (const float*)d_in[1];
    const int*   targets = (const int*)d_in[2];
    float* out = (float*)d_out;

    // workspace layout: pairq [3200 int] | partial [6400 f32]
    int*   pairq_g = (int*)d_ws;
    float* partial = (float*)(pairq_g + BS * NT);

    hipLaunchKernelGGL(hungarian_kernel, dim3(BS), dim3(256), 0, stream,
                       rec, loc, targets, pairq_g);
    hipLaunchKernelGGL(loss_kernel, dim3(BS * NT), dim3(64), 0, stream,
                       rec, loc, targets, pairq_g, partial);
    hipLaunchKernelGGL(finalize_kernel, dim3(1), dim3(256), 0, stream,
                       partial, out);
}

// Round 5
// 167.101 us; speedup vs baseline: 1.1646x; 1.1646x over previous
//
#include <hip/hip_runtime.h>
#include <hip/hip_bf16.h>
#include <math.h>

#define BS   128
#define NT   25
#define CREC 107
#define CLOC 25
#define QN   1024      // H*W = 32*32 queries = columns of the transposed cost
#define INFD 1e18

// focal-loss matcher cost. Fast transcendentals: the matcher only needs the
// optimal assignment, which is robust to ~1e-7 relative cost perturbation
// (verified: absmax 0.0 in R4 with this exact function).
__device__ __forceinline__ float focal_cost_f(float x) {
    float p   = 1.0f / (1.0f + __expf(-x));
    float neg = 0.75f * p * p * (-__logf(1.0f - p + 1e-8f));
    float pos = 0.25f * (1.0f - p) * (1.0f - p) * (-__logf(p + 1e-8f));
    return pos - neg;
}

// One block (256 thr = 4 waves) per batch. Columns PARTITIONED across waves:
// wave w owns q in [256w, 256w+256), lane owns one float4 (4 columns) =>
// per-lane dual state is v[4]+minv[4] f64 = 16 VGPRs (R4's replicated KPL=16
// layout spilled to scratch: 80 VGPRs, ~2-3us/iter of L2 spill traffic).
// Phase B: row-reduction init u[r]=min_j c[r][j] + greedy tight assignment.
// Phase C: JV shortest-augmenting-path only for argmin-collided rows
// (~3/batch, ~2-4 iters each). f64 duals on f32 costs = exact numpy
// semantics => the unique optimal assignment = scipy's answer.
__global__ __launch_bounds__(256)
void hungarian_kernel(const float* __restrict__ rec, const float* __restrict__ loc,
                      const int* __restrict__ targets, int* __restrict__ pairq_g) {
    const int b     = blockIdx.x;
    const int tid   = threadIdx.x;
    const int wave  = tid >> 6;
    const int lane  = tid & 63;
    const int qbase = (wave << 8) + (lane << 2);   // first of the 4 owned columns

    __shared__ int    way_s[QN + 1];
    __shared__ int    p_s[QN + 1];
    __shared__ double u_s[NT + 1];
    __shared__ int    t_s[NT];
    __shared__ float  bminv_s[NT][4];
    __shared__ int    bminq_s[NT][4];
    __shared__ float  rowmin_s[NT];
    __shared__ int    rowarg_s[NT];
    __shared__ int    unassigned_s[NT];
    __shared__ int    nun_s;
    __shared__ double candv_s[4];
    __shared__ int    candj_s[4];

    for (int j = tid; j <= QN; j += 256) { p_s[j] = 0; way_s[j] = 0; }
    if (tid < NT) t_s[tid] = targets[b * NT + tid];
    __syncthreads();

    const size_t rb0 = (size_t)b * CREC * QN;
    const size_t lb0 = (size_t)b * CLOC * QN;

    // ---- Phase B: row minima; each wave scans its 256 columns, 2-deep prefetch ----
    {
        float4 ra = *(const float4*)(rec + rb0 + (size_t)t_s[0] * QN + qbase);
        float4 la = *(const float4*)(loc + lb0 + qbase);
        for (int r = 0; r < NT; ++r) {
            float4 rn, ln;
            if (r + 1 < NT) {
                rn = *(const float4*)(rec + rb0 + (size_t)t_s[r + 1] * QN + qbase);
                ln = *(const float4*)(loc + lb0 + (size_t)(r + 1) * QN + qbase);
            }
            float c[4];
            c[0] = 2.0f * focal_cost_f(ra.x) + focal_cost_f(la.x);
            c[1] = 2.0f * focal_cost_f(ra.y) + focal_cost_f(la.y);
            c[2] = 2.0f * focal_cost_f(ra.z) + focal_cost_f(la.z);
            c[3] = 2.0f * focal_cost_f(ra.w) + focal_cost_f(la.w);
            float bv = c[0]; int bq = qbase;
            #pragma unroll
            for (int m = 1; m < 4; ++m)
                if (c[m] < bv) { bv = c[m]; bq = qbase + m; }   // strict < => first index
            #pragma unroll
            for (int off = 32; off; off >>= 1) {
                float ov = __shfl_xor(bv, off);
                int   oq = __shfl_xor(bq, off);
                if (ov < bv || (ov == bv && oq < bq)) { bv = ov; bq = oq; }
            }
            if (lane == 0) { bminv_s[r][wave] = bv; bminq_s[r][wave] = bq; }
            ra = rn; la = ln;
        }
    }
    __syncthreads();
    // cross-wave combine (wave q-ranges are ordered => strict < keeps first index)
    if (tid < NT) {
        float bv = bminv_s[tid][0]; int bq = bminq_s[tid][0];
        #pragma unroll
        for (int w = 1; w < 4; ++w) {
            float ov = bminv_s[tid][w]; int oq = bminq_s[tid][w];
            if (ov < bv || (ov == bv && oq < bq)) { bv = ov; bq = oq; }
        }
        rowmin_s[tid] = bv; rowarg_s[tid] = bq;
    }
    __syncthreads();
    // greedy tight assignment (serial, trivial)
    if (tid == 0) {
        nun_s = 0;
        for (int r = 0; r < NT; ++r) {
            u_s[r + 1] = (double)rowmin_s[r];
            int j = rowarg_s[r] + 1;
            if (p_s[j] == 0) p_s[j] = r + 1;
            else             unassigned_s[nun_s++] = r + 1;
        }
    }
    __syncthreads();
    const int nun = nun_s;

    // ---- Phase C: JV search for each collided row; lane owns cols qbase..qbase+3 ----
    double v[4] = {0.0, 0.0, 0.0, 0.0};

    for (int s = 0; s < nun; ++s) {
        const int i = unassigned_s[s];
        double minv[4] = {INFD, INFD, INFD, INFD};
        unsigned usedmask = 0;
        int j0 = 0;

        for (;;) {
            int i0;
            if (j0 == 0) {
                i0 = i;
            } else {
                int q0 = j0 - 1;
                if ((q0 >> 2) == tid) {          // owner thread of column q0
                    int m = q0 & 3;
                    usedmask |= 1u << m;
                    minv[m] = INFD;              // out of argmin & out of -=delta(free)
                }
                i0 = p_s[j0];                    // stable within a search
            }
            const double ui0 = u_s[i0];
            const float4 r4 = *(const float4*)(rec + rb0 + (size_t)t_s[i0 - 1] * QN + qbase);
            const float4 l4 = *(const float4*)(loc + lb0 + (size_t)(i0 - 1) * QN + qbase);
            float cf[4];
            cf[0] = 2.0f * focal_cost_f(r4.x) + focal_cost_f(l4.x);
            cf[1] = 2.0f * focal_cost_f(r4.y) + focal_cost_f(l4.y);
            cf[2] = 2.0f * focal_cost_f(r4.z) + focal_cost_f(l4.z);
            cf[3] = 2.0f * focal_cost_f(r4.w) + focal_cost_f(l4.w);

            // relax own free columns; lane-local lexicographic argmin
            double bestv = INFD; int bestj = QN + 2;
            #pragma unroll
            for (int m = 0; m < 4; ++m) {
                if (!(usedmask & (1u << m))) {
                    const int j = qbase + m + 1;
                    double cur = (double)cf[m] - ui0 - v[m];
                    if (cur < minv[m]) { minv[m] = cur; way_s[j] = j0; }  // own col: no race
                    double mv = minv[m];
                    if (mv < bestv || (mv == bestv && j < bestj)) { bestv = mv; bestj = j; }
                }
            }
            #pragma unroll
            for (int off = 32; off; off >>= 1) {
                double ov = __shfl_xor(bestv, off);
                int    oj = __shfl_xor(bestj, off);
                if (ov < bestv || (ov == bestv && oj < bestj)) { bestv = ov; bestj = oj; }
            }
            if (lane == 0) { candv_s[wave] = bestv; candj_s[wave] = bestj; }
            __syncthreads();
            // combine 4 wave candidates (uniform; wave q-ranges ordered)
            double delta = candv_s[0]; int j1 = candj_s[0];
            #pragma unroll
            for (int w = 1; w < 4; ++w) {
                double dv = candv_s[w]; int dj = candj_s[w];
                if (dv < delta || (dv == delta && dj < j1)) { delta = dv; j1 = dj; }
            }

            // v[used] -= delta, minv[free] -= delta (registers)
            #pragma unroll
            for (int m = 0; m < 4; ++m) {
                if (usedmask & (1u << m)) v[m]    -= delta;
                else                      minv[m] -= delta;
            }
            // u[p[used]] += delta: used columns hold distinct rows => distinct
            // LDS addresses across the whole block, conflict-free RMW.
            if (tid == 0) u_s[i] += delta;
            unsigned mm = usedmask;
            while (mm) {
                int m = __ffs(mm) - 1; mm &= mm - 1;
                u_s[p_s[qbase + m + 1]] += delta;
            }
            __syncthreads();   // fence u_s / candidates before next iteration

            j0 = j1;
            if (p_s[j0] == 0) break;
        }
        // augment along the alternating path (short, sequential)
        if (tid == 0) {
            int jj = j0;
            while (jj != 0) {
                int jn = way_s[jj];
                p_s[jj] = (jn == 0) ? i : p_s[jn];
                jj = jn;
            }
        }
        __syncthreads();
    }

    // emit matched pairs: column j assigned to target row p_s[j]-1
    for (int j = tid + 1; j <= QN; j += 256)
        if (p_s[j] > 0) pairq_g[b * NT + (p_s[j] - 1)] = j - 1;
}

// One wave per matched pair: CE over 107 (rec) and 25 (loc) classes at the
// matched query column. 3200 blocks => full latency hiding for the gathers.
__global__ __launch_bounds__(64)
void loss_kernel(const float* __restrict__ rec, const float* __restrict__ loc,
                 const int* __restrict__ targets, const int* __restrict__ pairq_g,
                 float* __restrict__ partial) {
    const int pid  = blockIdx.x;          // b*NT + t
    const int b    = pid / NT, t = pid % NT;
    const int lane = threadIdx.x;
    const int q    = pairq_g[pid];

    // rec CE over 107 classes at query q
    const float* rb = rec + (size_t)b * CREC * QN + q;
    float x0 = (lane < CREC)      ? rb[(size_t)lane * QN]        : -1e30f;
    float x1 = (lane + 64 < CREC) ? rb[(size_t)(lane + 64) * QN] : -1e30f;
    float mx = fmaxf(x0, x1);
    #pragma unroll
    for (int off = 32; off; off >>= 1) mx = fmaxf(mx, __shfl_xor(mx, off));
    float e = 0.0f;
    if (lane < CREC)      e += expf(x0 - mx);
    if (lane + 64 < CREC) e += expf(x1 - mx);
    #pragma unroll
    for (int off = 32; off; off >>= 1) e += __shfl_xor(e, off);
    float lse = mx + logf(e);

    // loc CE over 25 classes at query q, label = t
    const float* lb = loc + (size_t)b * CLOC * QN + q;
    float y = (lane < CLOC) ? lb[(size_t)lane * QN] : -1e30f;
    float my = y;
    #pragma unroll
    for (int off = 32; off; off >>= 1) my = fmaxf(my, __shfl_xor(my, off));
    float ey = (lane < CLOC) ? expf(y - my) : 0.0f;
    #pragma unroll
    for (int off = 32; off; off >>= 1) ey += __shfl_xor(ey, off);
    float lsey = my + logf(ey);

    if (lane == 0) {
        int lab = targets[pid];
        partial[pid]           = lse  - rb[(size_t)lab * QN];
        partial[BS * NT + pid] = lsey - lb[(size_t)t * QN];
    }
}

__global__ __launch_bounds__(256)
void finalize_kernel(const float* __restrict__ partial, float* __restrict__ out) {
    const int tid = threadIdx.x;
    float s0 = 0.0f, s1 = 0.0f;
    for (int i = tid; i < BS * NT; i += 256) {
        s0 += partial[i];
        s1 += partial[BS * NT + i];
    }
    __shared__ float a0[4], a1[4];
    #pragma unroll
    for (int off = 32; off; off >>= 1) { s0 += __shfl_xor(s0, off); s1 += __shfl_xor(s1, off); }
    if ((tid & 63) == 0) { a0[tid >> 6] = s0; a1[tid >> 6] = s1; }
    __syncthreads();
    if (tid == 0) {
        out[0] = (a0[0] + a0[1] + a0[2] + a0[3]) * (1.0f / (BS * NT));
        out[1] = (a1[0] + a1[1] + a1[2] + a1[3]) * (1.0f / (BS * NT));
    }
}

extern "C" void kernel_launch(void* const* d_in, const int* in_sizes, int n_in,
                              void* d_out, int out_size, void* d_ws, size_t ws_size,
                              hipStream_t stream) {
    (void)in_sizes; (void)n_in; (void)out_size; (void)ws_size;
    const float* rec     = (const float*)d_in[0];
    const float* loc     = (const float*)d_in[1];
    const int*   targets = (const int*)d_in[2];
    float* out = (float*)d_out;

    // workspace layout: pairq [3200 int] | partial [6400 f32]
    int*   pairq_g = (int*)d_ws;
    float* partial = (float*)(pairq_g + BS * NT);

    hipLaunchKernelGGL(hungarian_kernel, dim3(BS), dim3(256), 0, stream,
                       rec, loc, targets, pairq_g);
    hipLaunchKernelGGL(loss_kernel, dim3(BS * NT), dim3(64), 0, stream,
                       rec, loc, targets, pairq_g, partial);
    hipLaunchKernelGGL(finalize_kernel, dim3(1), dim3(256), 0, stream,
                       partial, out);
}

// Round 6
// 155.320 us; speedup vs baseline: 1.2529x; 1.0758x over previous
//
#include <hip/hip_runtime.h>
#include <hip/hip_bf16.h>
#include <math.h>

#define BS   128
#define NT   25
#define CREC 107
#define CLOC 25
#define QN   1024      // H*W = 32*32 queries = columns of the transposed cost
#define INFD 1e18
// swizzled index for way[] (kills stride-4 bank conflicts: consecutive tids
// hit consecutive addresses within an m-plane)
#define WSTR 257
__device__ __forceinline__ int widx(int j) {   // j in 1..QN
    int q = j - 1;
    return (q & 3) * WSTR + (q >> 2);
}

// focal-loss matcher cost. Fast transcendentals: the matcher only needs the
// optimal assignment, which is robust to ~1e-7 relative cost perturbation
// (verified: absmax 0.0 in R4/R5 with this exact function).
__device__ __forceinline__ float focal_cost_f(float x) {
    float p   = 1.0f / (1.0f + __expf(-x));
    float neg = 0.75f * p * p * (-__logf(1.0f - p + 1e-8f));
    float pos = 0.25f * (1.0f - p) * (1.0f - p) * (-__logf(p + 1e-8f));
    return pos - neg;
}

// Phase B as its own dispatch: 3200 blocks (one per cost row), 256 threads,
// 4 columns/thread. Computes rowmin + first-index argmin exactly.
__global__ __launch_bounds__(256)
void rowmin_kernel(const float* __restrict__ rec, const float* __restrict__ loc,
                   const int* __restrict__ targets,
                   float* __restrict__ rowmin_g, int* __restrict__ rowarg_g) {
    const int pid   = blockIdx.x;          // b*NT + r
    const int b     = pid / NT, r = pid % NT;
    const int tid   = threadIdx.x;
    const int qbase = tid << 2;
    const int tc    = targets[pid];

    float4 r4 = *(const float4*)(rec + ((size_t)b * CREC + tc) * QN + qbase);
    float4 l4 = *(const float4*)(loc + ((size_t)b * CLOC + r)  * QN + qbase);
    float c[4];
    c[0] = 2.0f * focal_cost_f(r4.x) + focal_cost_f(l4.x);
    c[1] = 2.0f * focal_cost_f(r4.y) + focal_cost_f(l4.y);
    c[2] = 2.0f * focal_cost_f(r4.z) + focal_cost_f(l4.z);
    c[3] = 2.0f * focal_cost_f(r4.w) + focal_cost_f(l4.w);

    float bv = c[0]; int bq = qbase;
    #pragma unroll
    for (int m = 1; m < 4; ++m)
        if (c[m] < bv) { bv = c[m]; bq = qbase + m; }   // strict < => first index
    #pragma unroll
    for (int off = 32; off; off >>= 1) {
        float ov = __shfl_xor(bv, off);
        int   oq = __shfl_xor(bq, off);
        if (ov < bv || (ov == bv && oq < bq)) { bv = ov; bq = oq; }
    }
    __shared__ float bmv[4];
    __shared__ int   bmq[4];
    if ((tid & 63) == 0) { bmv[tid >> 6] = bv; bmq[tid >> 6] = bq; }
    __syncthreads();
    if (tid == 0) {
        float fv = bmv[0]; int fq = bmq[0];
        #pragma unroll
        for (int w = 1; w < 4; ++w) {
            float ov = bmv[w]; int oq = bmq[w];
            if (ov < fv || (ov == fv && oq < fq)) { fv = ov; fq = oq; }
        }
        rowmin_g[pid] = fv; rowarg_g[pid] = fq;
    }
}

// Phase C: greedy tight assignment from row minima, then JV shortest-
// augmenting-path only for argmin-collided rows. One barrier per search
// iteration: u-updates are hoisted to search end via delta-sum snapshots
// (bit-identical: a row's u is only ever READ at its pre-search value — each
// row is reached at most once per search, before any delta applies to it).
// f64 duals on f32 costs = exact numpy semantics => unique optimum = scipy.
__global__ __launch_bounds__(256)
void search_kernel(const float* __restrict__ rec, const float* __restrict__ loc,
                   const int* __restrict__ targets,
                   const float* __restrict__ rowmin_g, const int* __restrict__ rowarg_g,
                   int* __restrict__ pairq_g) {
    const int b     = blockIdx.x;
    const int tid   = threadIdx.x;
    const int wave  = tid >> 6;
    const int lane  = tid & 63;
    const int qbase = tid << 2;          // first of the 4 owned columns

    __shared__ int    way_s[4 * WSTR];
    __shared__ int    p_s[QN + 1];
    __shared__ double u_s[NT + 1];
    __shared__ int    t_s[NT];
    __shared__ float  rowmin_s[NT];
    __shared__ int    rowarg_s[NT];
    __shared__ int    unassigned_s[NT];
    __shared__ int    nun_s;
    __shared__ double candv_s[2][4];
    __shared__ int    candj_s[2][4];

    for (int j = tid; j <= QN; j += 256) p_s[j] = 0;
    if (tid < NT) {
        t_s[tid]      = targets[b * NT + tid];
        rowmin_s[tid] = rowmin_g[b * NT + tid];
        rowarg_s[tid] = rowarg_g[b * NT + tid];
    }
    __syncthreads();

    // greedy tight assignment (serial, trivial)
    if (tid == 0) {
        nun_s = 0;
        for (int r = 0; r < NT; ++r) {
            u_s[r + 1] = (double)rowmin_s[r];
            int j = rowarg_s[r] + 1;
            if (p_s[j] == 0) p_s[j] = r + 1;
            else             unassigned_s[nun_s++] = r + 1;
        }
    }
    __syncthreads();
    const int nun = nun_s;

    const size_t rb0 = (size_t)b * CREC * QN;
    const size_t lb0 = (size_t)b * CLOC * QN;

    double v[4] = {0.0, 0.0, 0.0, 0.0};

    for (int s = 0; s < nun; ++s) {
        const int i = unassigned_s[s];
        double minv[4] = {INFD, INFD, INFD, INFD};
        double snap[4] = {0.0, 0.0, 0.0, 0.0};
        double dsum    = 0.0;
        unsigned usedmask = 0;
        int j0 = 0;
        int parity = 0;

        for (;;) {
            int i0;
            if (j0 == 0) {
                i0 = i;
            } else {
                int q0 = j0 - 1;
                if ((q0 >> 2) == tid) {          // owner thread of column q0
                    int m = q0 & 3;
                    usedmask |= 1u << m;
                    minv[m] = INFD;              // out of argmin & out of -=delta(free)
                    snap[m] = dsum;              // deltas before this iter don't apply
                }
                i0 = p_s[j0];                    // p stable within a search
            }
            const double ui0 = u_s[i0];          // read-only in-loop: pre-search value
            const float4 r4 = *(const float4*)(rec + rb0 + (size_t)t_s[i0 - 1] * QN + qbase);
            const float4 l4 = *(const float4*)(loc + lb0 + (size_t)(i0 - 1) * QN + qbase);
            float cf[4];
            cf[0] = 2.0f * focal_cost_f(r4.x) + focal_cost_f(l4.x);
            cf[1] = 2.0f * focal_cost_f(r4.y) + focal_cost_f(l4.y);
            cf[2] = 2.0f * focal_cost_f(r4.z) + focal_cost_f(l4.z);
            cf[3] = 2.0f * focal_cost_f(r4.w) + focal_cost_f(l4.w);

            // relax own free columns; lane-local lexicographic argmin
            double bestv = INFD; int bestj = QN + 2;
            #pragma unroll
            for (int m = 0; m < 4; ++m) {
                if (!(usedmask & (1u << m))) {
                    const int j = qbase + m + 1;
                    double cur = (double)cf[m] - ui0 - v[m];
                    if (cur < minv[m]) { minv[m] = cur; way_s[widx(j)] = j0; }
                    double mv = minv[m];
                    if (mv < bestv || (mv == bestv && j < bestj)) { bestv = mv; bestj = j; }
                }
            }
            #pragma unroll
            for (int off = 32; off; off >>= 1) {
                double ov = __shfl_xor(bestv, off);
                int    oj = __shfl_xor(bestj, off);
                if (ov < bestv || (ov == bestv && oj < bestj)) { bestv = ov; bestj = oj; }
            }
            if (lane == 0) { candv_s[parity][wave] = bestv; candj_s[parity][wave] = bestj; }
            __syncthreads();                     // the ONE barrier per iteration
            // combine 4 wave candidates (uniform; wave q-ranges ordered)
            double delta = candv_s[parity][0]; int j1 = candj_s[parity][0];
            #pragma unroll
            for (int w = 1; w < 4; ++w) {
                double dv = candv_s[parity][w]; int dj = candj_s[parity][w];
                if (dv < delta || (dv == delta && dj < j1)) { delta = dv; j1 = dj; }
            }
            parity ^= 1;
            dsum += delta;

            #pragma unroll
            for (int m = 0; m < 4; ++m) {
                if (usedmask & (1u << m)) v[m]    -= delta;
                else                      minv[m] -= delta;
            }
            j0 = j1;
            if (p_s[j0] == 0) break;
        }

        // end-of-search u updates: u[p[j]] += dsum - snap(j) for used cols,
        // u[i] += dsum for the root. Distinct rows => conflict-free LDS RMW.
        if (tid == 0) u_s[i] += dsum;
        unsigned mm = usedmask;
        while (mm) {
            int m = __ffs(mm) - 1; mm &= mm - 1;
            u_s[p_s[qbase + m + 1]] += dsum - snap[m];
        }
        __syncthreads();
        // augment along the alternating path (short, sequential)
        if (tid == 0) {
            int jj = j0;
            while (jj != 0) {
                int jn = way_s[widx(jj)];
                p_s[jj] = (jn == 0) ? i : p_s[jn];
                jj = jn;
            }
        }
        __syncthreads();
    }

    // emit matched pairs: column j assigned to target row p_s[j]-1
    for (int j = tid + 1; j <= QN; j += 256)
        if (p_s[j] > 0) pairq_g[b * NT + (p_s[j] - 1)] = j - 1;
}

// One wave per matched pair: CE over 107 (rec) and 25 (loc) classes at the
// matched query column. 3200 blocks => full latency hiding for the gathers.
__global__ __launch_bounds__(64)
void loss_kernel(const float* __restrict__ rec, const float* __restrict__ loc,
                 const int* __restrict__ targets, const int* __restrict__ pairq_g,
                 float* __restrict__ partial) {
    const int pid  = blockIdx.x;          // b*NT + t
    const int b    = pid / NT, t = pid % NT;
    const int lane = threadIdx.x;
    const int q    = pairq_g[pid];

    // rec CE over 107 classes at query q
    const float* rb = rec + (size_t)b * CREC * QN + q;
    float x0 = (lane < CREC)      ? rb[(size_t)lane * QN]        : -1e30f;
    float x1 = (lane + 64 < CREC) ? rb[(size_t)(lane + 64) * QN] : -1e30f;
    float mx = fmaxf(x0, x1);
    #pragma unroll
    for (int off = 32; off; off >>= 1) mx = fmaxf(mx, __shfl_xor(mx, off));
    float e = 0.0f;
    if (lane < CREC)      e += expf(x0 - mx);
    if (lane + 64 < CREC) e += expf(x1 - mx);
    #pragma unroll
    for (int off = 32; off; off >>= 1) e += __shfl_xor(e, off);
    float lse = mx + logf(e);

    // loc CE over 25 classes at query q, label = t
    const float* lb = loc + (size_t)b * CLOC * QN + q;
    float y = (lane < CLOC) ? lb[(size_t)lane * QN] : -1e30f;
    float my = y;
    #pragma unroll
    for (int off = 32; off; off >>= 1) my = fmaxf(my, __shfl_xor(my, off));
    float ey = (lane < CLOC) ? expf(y - my) : 0.0f;
    #pragma unroll
    for (int off = 32; off; off >>= 1) ey += __shfl_xor(ey, off);
    float lsey = my + logf(ey);

    if (lane == 0) {
        int lab = targets[pid];
        partial[pid]           = lse  - rb[(size_t)lab * QN];
        partial[BS * NT + pid] = lsey - lb[(size_t)t * QN];
    }
}

__global__ __launch_bounds__(256)
void finalize_kernel(const float* __restrict__ partial, float* __restrict__ out) {
    const int tid = threadIdx.x;
    float s0 = 0.0f, s1 = 0.0f;
    for (int i = tid; i < BS * NT; i += 256) {
        s0 += partial[i];
        s1 += partial[BS * NT + i];
    }
    __shared__ float a0[4], a1[4];
    #pragma unroll
    for (int off = 32; off; off >>= 1) { s0 += __shfl_xor(s0, off); s1 += __shfl_xor(s1, off); }
    if ((tid & 63) == 0) { a0[tid >> 6] = s0; a1[tid >> 6] = s1; }
    __syncthreads();
    if (tid == 0) {
        out[0] = (a0[0] + a0[1] + a0[2] + a0[3]) * (1.0f / (BS * NT));
        out[1] = (a1[0] + a1[1] + a1[2] + a1[3]) * (1.0f / (BS * NT));
    }
}

extern "C" void kernel_launch(void* const* d_in, const int* in_sizes, int n_in,
                              void* d_out, int out_size, void* d_ws, size_t ws_size,
                              hipStream_t stream) {
    (void)in_sizes; (void)n_in; (void)out_size; (void)ws_size;
    const float* rec     = (const float*)d_in[0];
    const float* loc     = (const float*)d_in[1];
    const int*   targets = (const int*)d_in[2];
    float* out = (float*)d_out;

    // workspace layout: rowmin f32[3200] | rowarg i32[3200] | pairq i32[3200] | partial f32[6400]
    float* rowmin_g = (float*)d_ws;
    int*   rowarg_g = (int*)(rowmin_g + BS * NT);
    int*   pairq_g  = (int*)(rowarg_g + BS * NT);
    float* partial  = (float*)(pairq_g + BS * NT);

    hipLaunchKernelGGL(rowmin_kernel, dim3(BS * NT), dim3(256), 0, stream,
                       rec, loc, targets, rowmin_g, rowarg_g);
    hipLaunchKernelGGL(search_kernel, dim3(BS), dim3(256), 0, stream,
                       rec, loc, targets, rowmin_g, rowarg_g, pairq_g);
    hipLaunchKernelGGL(loss_kernel, dim3(BS * NT), dim3(64), 0, stream,
                       rec, loc, targets, pairq_g, partial);
    hipLaunchKernelGGL(finalize_kernel, dim3(1), dim3(256), 0, stream,
                       partial, out);
}